// Round 1
// baseline (1913.064 us; speedup 1.0000x reference)
//
#include <hip/hip_runtime.h>

#define TT 4096
#define EE 256
#define HH 10
#define GG 40      // 4*H
#define OO 50257
#define CH 128     // steps per LDS chunk in the scan
#define NCH (TT/CH)
#define TB 64      // timesteps per block in the output GEMM

typedef float v2f __attribute__((ext_vector_type(2)));

__device__ __forceinline__ float fexp(float x) {
    return __builtin_amdgcn_exp2f(x * 1.44269504088896340736f);
}
__device__ __forceinline__ float frcp(float x) {
    return __builtin_amdgcn_rcpf(x);
}
__device__ __forceinline__ float fsig(float x) {
    return frcp(1.f + fexp(-x));
}
__device__ __forceinline__ float ftanh(float x) {
    // 1 - 2/(e^{2x}+1); stable at both extremes
    return 1.f - 2.f * frcp(fexp(2.f * x) + 1.f);
}

// ---------------- Kernel 1: xg[t][j] = emb[x[t]] . w_ih[j] + b_ih[j] + b_hh[j]
__global__ __launch_bounds__(256) void k_xgate(const int* __restrict__ x,
                                               const float* __restrict__ emb,
                                               const float* __restrict__ w_ih,
                                               const float* __restrict__ b_ih,
                                               const float* __restrict__ b_hh,
                                               float* __restrict__ xg) {
    int idx = blockIdx.x * blockDim.x + threadIdx.x;   // t*40 + j
    if (idx >= TT * GG) return;
    int t = idx / GG;
    int j = idx - t * GG;
    const float4* er = (const float4*)(emb + (long long)x[t] * EE);
    const float4* wr = (const float4*)(w_ih + j * EE);
    float4 a = make_float4(0.f, 0.f, 0.f, 0.f);
#pragma unroll 8
    for (int e = 0; e < EE / 4; ++e) {
        float4 u = er[e], w = wr[e];
        a.x += u.x * w.x; a.y += u.y * w.y;
        a.z += u.z * w.z; a.w += u.w * w.w;
    }
    xg[idx] = (a.x + a.y) + (a.z + a.w) + b_ih[j] + b_hh[j];
}

// ---------------- Kernel 2: sequential LSTM scan (1 block, 2 waves)
// wave 0 = scanner (lanes 0..9 own hidden units, readlane broadcast of h)
// wave 1 = loader  (double-buffers xg chunks into LDS)
// Gate math packed as float2 -> v_pk_fma_f32: (i,f) and (g,o) pairs,
// each dot split into two independent chains (even/odd j) to halve latency.
__global__ __launch_bounds__(128) void k_scan(const float* __restrict__ xg,
                                              const float* __restrict__ w_hh,
                                              float* __restrict__ hs) {
    __shared__ float sxg[2][CH * GG];
    const int lane = threadIdx.x & 63;
    const int wave = threadIdx.x >> 6;
    const int k = (lane < HH) ? lane : 0;   // clamp idle lanes; only lanes<10 store

    v2f wif[HH], wgo[HH];
    if (wave == 1) {
        const float4* src = (const float4*)xg;
        float4* dst = (float4*)sxg[0];
        for (int i = lane; i < CH * GG / 4; i += 64) dst[i] = src[i];
    } else {
#pragma unroll
        for (int j = 0; j < HH; ++j) {
            wif[j].x = w_hh[(0 * HH + k) * HH + j];
            wif[j].y = w_hh[(1 * HH + k) * HH + j];
            wgo[j].x = w_hh[(2 * HH + k) * HH + j];
            wgo[j].y = w_hh[(3 * HH + k) * HH + j];
        }
    }
    __syncthreads();

    float h = 0.f, c = 0.f;
    for (int cc = 0; cc < NCH; ++cc) {
        if (wave == 1) {
            if (cc + 1 < NCH) {
                const float4* src = (const float4*)(xg + (size_t)(cc + 1) * CH * GG);
                float4* dst = (float4*)sxg[(cc + 1) & 1];
                for (int i = lane; i < CH * GG / 4; i += 64) dst[i] = src[i];
            }
        } else {
            const float* bx = sxg[cc & 1];
            float nxi = bx[k], nxf = bx[HH + k], nxg = bx[2 * HH + k], nxo = bx[3 * HH + k];
            for (int s = 0; s < CH; ++s) {
                v2f aif0, ago0, aif1, ago1;
                aif0.x = nxi; aif0.y = nxf;
                ago0.x = nxg; ago0.y = nxo;
                aif1.x = 0.f; aif1.y = 0.f;
                ago1.x = 0.f; ago1.y = 0.f;
                if (s + 1 < CH) {   // prefetch next step's xg (hides LDS latency)
                    const float* nr = bx + (s + 1) * GG;
                    nxi = nr[k]; nxf = nr[HH + k]; nxg = nr[2 * HH + k]; nxo = nr[3 * HH + k];
                }
#pragma unroll
                for (int j = 0; j < HH; ++j) {
                    float hj = __uint_as_float(
                        __builtin_amdgcn_readlane(__float_as_uint(h), j));
                    v2f hh; hh.x = hj; hh.y = hj;
                    if (j & 1) { aif1 += wif[j] * hh; ago1 += wgo[j] * hh; }
                    else       { aif0 += wif[j] * hh; ago0 += wgo[j] * hh; }
                }
                v2f aif = aif0 + aif1;
                v2f ago = ago0 + ago1;
                float i_ = fsig(aif.x), f_ = fsig(aif.y);
                float g_ = ftanh(ago.x), o_ = fsig(ago.y);
                c = f_ * c + i_ * g_;
                h = o_ * ftanh(c);
                if (lane < HH) hs[(size_t)(cc * CH + s) * HH + lane] = h;
            }
        }
        __syncthreads();
    }
}

// ---------------- Kernel 3: logits[t][o] = hs[t] . W_out[o] + b_out[o]
// Block: 256 threads, 4 strided columns each (coalesced dword stores),
// TB timesteps, processed in pairs (float2) to enable v_pk_fma_f32.
// Stores are nontemporal: 823 MB write-once stream, keep it out of L2/L3.
__global__ __launch_bounds__(256) void k_logits(const float* __restrict__ hs,
                                                const float* __restrict__ W,
                                                const float* __restrict__ b,
                                                float* __restrict__ out) {
    __shared__ float sh[HH * TB];   // transposed: sh[j][t]
    const int tid = threadIdx.x;
    const int tb = blockIdx.y;
    const long long obase = (long long)blockIdx.x * 1024;

    for (int i = tid; i < TB * HH; i += 256) {
        int t = i / HH;
        int j = i - t * HH;
        sh[j * TB + t] = hs[(size_t)tb * TB * HH + i];
    }
    __syncthreads();

    float w[4][HH];
    float bb[4];
    int oi[4];
#pragma unroll
    for (int i2 = 0; i2 < 4; ++i2) {
        long long o = obase + i2 * 256 + tid;
        oi[i2] = (o < OO) ? (int)o : -1;
        bb[i2] = (oi[i2] >= 0) ? b[oi[i2]] : 0.f;
#pragma unroll
        for (int j = 0; j < HH; ++j)
            w[i2][j] = (oi[i2] >= 0) ? W[(size_t)oi[i2] * HH + j] : 0.f;
    }

    const long long trow = (long long)tb * TB;
    for (int tp = 0; tp < TB / 2; ++tp) {
        float2 hv[HH];
#pragma unroll
        for (int j = 0; j < HH; ++j)
            hv[j] = ((const float2*)(sh + j * TB))[tp];
        const long long t0 = trow + 2 * tp;
#pragma unroll
        for (int i2 = 0; i2 < 4; ++i2) {
            if (oi[i2] < 0) continue;
            float ax = bb[i2], ay = bb[i2];
#pragma unroll
            for (int j = 0; j < HH; ++j) {
                ax += w[i2][j] * hv[j].x;
                ay += w[i2][j] * hv[j].y;
            }
            __builtin_nontemporal_store(ax, out + t0 * OO + oi[i2]);
            __builtin_nontemporal_store(ay, out + (t0 + 1) * OO + oi[i2]);
        }
    }
}

extern "C" void kernel_launch(void* const* d_in, const int* in_sizes, int n_in,
                              void* d_out, int out_size, void* d_ws, size_t ws_size,
                              hipStream_t stream) {
    const int*   x    = (const int*)  d_in[0];
    const float* emb  = (const float*)d_in[1];
    const float* w_ih = (const float*)d_in[2];
    const float* w_hh = (const float*)d_in[3];
    const float* b_ih = (const float*)d_in[4];
    const float* b_hh = (const float*)d_in[5];
    const float* Wout = (const float*)d_in[6];
    const float* bout = (const float*)d_in[7];
    float* out = (float*)d_out;

    float* xg = (float*)d_ws;                 // [4096][40]
    float* hs = xg + (size_t)TT * GG;         // [4096][10]  (total ws use: 820 KB)

    k_xgate<<<(TT * GG + 255) / 256, 256, 0, stream>>>(x, emb, w_ih, b_ih, b_hh, xg);
    k_scan<<<1, 128, 0, stream>>>(xg, w_hh, hs);
    dim3 g3((OO + 1023) / 1024, TT / TB);
    k_logits<<<g3, 256, 0, stream>>>(hs, Wout, bout, out);
}